// Round 4
// baseline (545.176 us; speedup 1.0000x reference)
//
#include <hip/hip_runtime.h>
#include <cmath>

typedef __attribute__((ext_vector_type(8))) _Float16 half8;
typedef __attribute__((ext_vector_type(8))) unsigned short ushort8;
typedef __attribute__((ext_vector_type(4))) float f32x4;

#define HH 7168
#define NE 256
#define NQ 224        // K32 chunks
#define NWND 56       // 128-K windows
#define NITER 112     // 64-K iterations
#define TOPK 8
#define TOPKG 4
#define WSC 1024.f
#define INV_WS (1.f/1024.f)
#define C1 (1.f/2048.f)       // 2^-11
#define C2 (1.f/4194304.f)    // 2^-22

// 2-level f16 split: x = h + m*2^-11, residual ~2^-25|x|
__device__ __forceinline__ void split2(float x, unsigned short& h, unsigned short& m){
  const _Float16 hh = (_Float16)x;
  const float r = x - (float)hh;                 // exact
  const _Float16 mm = (_Float16)(r * 2048.f);
  h = __builtin_bit_cast(unsigned short, hh);
  m = __builtin_bit_cast(unsigned short, mm);
}

// W*1024 -> (h,m) f16 in MFMA B-fragment order, coalesced writes.
// slot(q,nt,L) holds B[k=32q+8(L>>4)+j][e=16nt+(L&15)], j=0..7.
__global__ __launch_bounds__(256) void prep_w(const float* __restrict__ wgt,
                                              unsigned short* __restrict__ bh,
                                              unsigned short* __restrict__ bm){
  const int b = blockIdx.x;                 // 896 = 16 nt * 56 q-groups
  const int nt = b & 15, qb = (b >> 4) * 4;
  const int w = threadIdx.x >> 6, L = threadIdx.x & 63;
  const int q = qb + w;
  const int e = nt*16 + (L & 15);
  const int k0 = 32*q + 8*(L >> 4);
  const float4 a0 = *(const float4*)(wgt + (size_t)e*HH + k0);
  const float4 a1 = *(const float4*)(wgt + (size_t)e*HH + k0 + 4);
  const float v[8] = {a0.x,a0.y,a0.z,a0.w,a1.x,a1.y,a1.z,a1.w};
  ushort8 h8, m8;
#pragma unroll
  for(int j=0;j<8;j++){ unsigned short hh,mm; split2(v[j]*WSC, hh, mm); h8[j]=hh; m8[j]=mm; }
  const size_t base = ((size_t)(q*16+nt)*64 + L)*8;
  *(ushort8*)(bh+base) = h8;
  *(ushort8*)(bm+base) = m8;
}

// ---------------- GEMM: 64-K iters, depth-2 B ring, counted vmcnt ----------------
// Block = 32 tok x 128 exp (slice), 512 thr / 8 waves (2mt x 4nt).
// One barrier per 64-K iter (112 total), 16 MFMA/wave between barriers.
// B: SIX 16KB LDS slots; iter i reads q{2i,2i+1}, issues glds for q{2i+4,2i+5}
//   (~2000cy cover). Set-based vmcnt ledger (robust to intra-iter load reorder):
//   allowed-in-flight at barrier = this iter's issues -> even vmcnt(6) [4B+2A],
//   odd vmcnt(4)+lgkm(0) [4B; A ds_writes publish], tail vmcnt(0).
// A: 128-K windows, ring 2 x 16KB; gload at even iter (wnd+1), split2+swizzled
//   ds_write at odd iter. Split2 once per window (no redundancy).
// LDS 96+32 = 128KB -> 1 block/CU, 2 waves/SIMD (m201 regime); setprio on MFMA.
#define AB(aw,lvl,mt,q,row) (((((aw)*4+(lvl)*2+(mt))*4+(q))*64+(row))*16)
__device__ __forceinline__ int swz(int bo){ return bo ^ (((bo >> 8) & 7) << 4); }

__device__ __forceinline__ void glds16(const void* g, void* l){
  __builtin_amdgcn_global_load_lds(
      (const __attribute__((address_space(1))) unsigned int*)g,
      (__attribute__((address_space(3))) unsigned int*)l, 16, 0, 0);
}

#define KAHAN do{ \
  _Pragma("unroll") \
  for(int cc=0;cc<2;cc++) \
    _Pragma("unroll") \
    for(int r=0;r<4;r++){ \
      const float v = c0[cc][r] + c1[cc][r]*C1 + c2[cc][r]*C2; \
      const float y = v - kcmp[cc][r]; \
      const float t = ksum[cc][r] + y; \
      kcmp[cc][r] = (t - ksum[cc][r]) - y; \
      ksum[cc][r] = t; \
    } \
}while(0)

__global__ __launch_bounds__(512,2)
void gemm(const float* __restrict__ hs,
          const unsigned short* __restrict__ bhp,
          const unsigned short* __restrict__ bmp,
          float* __restrict__ lgout){
  __shared__ __align__(16) unsigned char blds[98304];  // 6 slots x (2lvl x 8nt x 1KB)
  __shared__ __align__(16) unsigned char alds[32768];  // 2win x 2lvl x 2mt x 4q x 64row x 16B

  const int tid = threadIdx.x, lane = tid & 63, w = tid >> 6;
  const int b = blockIdx.x;
  const int slice = (b >> 2) & 1;
  const int tg = (b >> 3)*4 + (b & 3);     // 0..255
  const int tb = tg*32, eb = slice*128;
  const int mtp = w >> 2, ntp = w & 3;

  f32x4 ksum[2], kcmp[2], c0[2], c1[2], c2[2];
#pragma unroll
  for(int cc=0;cc<2;cc++){ ksum[cc]=f32x4{0,0,0,0}; kcmp[cc]=f32x4{0,0,0,0}; }

  // A staging ids: 16 thr/token, thread covers 8 consecutive k of a 128-K window
  const int tokS = tid >> 4, kidx = tid & 15;
  const int mtS = tokS >> 4, m16S = tokS & 15;
  const int qS = kidx >> 2, kgS = kidx & 3;
  const int rowS = kgS*16 + m16S;
  const float* agp = hs + (size_t)(tb + tokS)*HH + kidx*8;
  float4 ga[2];

  auto stage = [&](int aw){
    unsigned short h[8], m[8];
    const float* gv = (const float*)ga;
#pragma unroll
    for(int p=0;p<8;p++) split2(gv[p], h[p], m[p]);
    ushort8 h8, m8;
#pragma unroll
    for(int j=0;j<8;j++){ h8[j]=h[j]; m8[j]=m[j]; }
    *(ushort8*)&alds[swz(AB(aw,0,mtS,qS,rowS))] = h8;
    *(ushort8*)&alds[swz(AB(aw,1,mtS,qS,rowS))] = m8;
  };

  // B issue: wave w owns (lvl = w>>2, nt pair (w&3)*2), 2 glds per 32-K chunk
  const unsigned short* bsrc = (w >= 4 ? bmp : bhp)
      + ((size_t)((slice*8 + (w&3)*2)*64 + lane))*8;
  const int bdst = (w>>2)*8192 + (w&3)*2048;
  auto issueB = [&](int slotoff, int q32){
    const unsigned short* s0 = bsrc + (size_t)q32*8192;
    glds16(s0,       &blds[slotoff + bdst]);
    glds16(s0 + 512, &blds[slotoff + bdst + 1024]);
  };

  auto compute = [&](int awr, int qloc, int bco){
    const half8 ah = *(const half8*)&alds[swz(AB(awr,0,mtp,qloc,lane))];
    const half8 am = *(const half8*)&alds[swz(AB(awr,1,mtp,qloc,lane))];
    half8 Bh[2], Bm[2];
#pragma unroll
    for(int ntl=0;ntl<2;ntl++){
      Bh[ntl] = *(const half8*)&blds[bco + (ntp*2+ntl)*1024 + lane*16];
      Bm[ntl] = *(const half8*)&blds[bco + 8192 + (ntp*2+ntl)*1024 + lane*16];
    }
    __builtin_amdgcn_s_setprio(1);
#pragma unroll
    for(int ntl=0;ntl<2;ntl++){
      c0[ntl] = __builtin_amdgcn_mfma_f32_16x16x32_f16(ah, Bh[ntl], c0[ntl], 0,0,0);
      c1[ntl] = __builtin_amdgcn_mfma_f32_16x16x32_f16(ah, Bm[ntl], c1[ntl], 0,0,0);
      c1[ntl] = __builtin_amdgcn_mfma_f32_16x16x32_f16(am, Bh[ntl], c1[ntl], 0,0,0);
      c2[ntl] = __builtin_amdgcn_mfma_f32_16x16x32_f16(am, Bm[ntl], c2[ntl], 0,0,0);
    }
    __builtin_amdgcn_s_setprio(0);
  };

  // ---- prologue: A window 0 + B q0..3; leave q2,q3 in flight
  ga[0] = *(const float4*)agp; ga[1] = *(const float4*)(agp+4);
  issueB(0,     0);
  issueB(16384, 1);
  issueB(32768, 2);
  issueB(49152, 3);
  stage(0);                                   // auto-waits ga
  asm volatile("s_waitcnt vmcnt(4) lgkmcnt(0)" ::: "memory");
  __builtin_amdgcn_s_barrier();

  int sA = 0;   // slot of q=4*wnd (values cycle 0,4,2)
#pragma unroll 1
  for(int wnd=0; wnd<NWND; ++wnd){
    const int awr = wnd & 1;
    const int s0 = sA;
    const int s1 = s0+1;                      // sA even -> s1 < 6
    int s2 = s0+2; if(s2>=6) s2-=6;
    int s3 = s2+1;
    int s4 = s2+2; if(s4>=6) s4-=6;
    int s5 = s4+1;
    const int q0 = 4*wnd;
    const bool more = (wnd+1 < NWND);

    // ===== even iter (i=2wnd): read q0,q0+1; issue B(q0+4,q0+5); gload A(wnd+1)
    if(more){
      const float* ap = agp + (size_t)(wnd+1)*128;
      ga[0] = *(const float4*)ap; ga[1] = *(const float4*)(ap+4);
      issueB(s4*16384, q0+4);
      issueB(s5*16384, q0+5);
    }
#pragma unroll
    for(int cc=0;cc<2;cc++){ c0[cc]=f32x4{0,0,0,0}; c1[cc]=f32x4{0,0,0,0}; c2[cc]=f32x4{0,0,0,0}; }
    compute(awr, 0, s0*16384);
    compute(awr, 1, s1*16384);
    if(more){ asm volatile("s_waitcnt vmcnt(6)" ::: "memory"); }
    else    { asm volatile("s_waitcnt vmcnt(0)" ::: "memory"); }
    __builtin_amdgcn_s_barrier();

    // ===== odd iter (i=2wnd+1): read q0+2,q0+3; issue B(q0+6,q0+7); stage A(wnd+1)
    if(more){
      issueB(s0*16384, q0+6);                 // slot s0: its readers finished last iter
      issueB(s1*16384, q0+7);
    }
    compute(awr, 2, s2*16384);
    compute(awr, 3, s3*16384);
    if(more) stage(awr^1);
    KAHAN;
    if(more){
      asm volatile("s_waitcnt vmcnt(4) lgkmcnt(0)" ::: "memory");
      __builtin_amdgcn_s_barrier();
    }
    sA += 4; if(sA>=6) sA-=6;
  }

  // epilogue: C layout col=lane&15 (expert), row=(lane>>4)*4+r (token); undo W scale
#pragma unroll
  for(int ntl=0;ntl<2;ntl++)
#pragma unroll
    for(int r=0;r<4;r++){
      const int tok = mtp*16 + (lane>>4)*4 + r;
      const int e = (ntp*2+ntl)*16 + (lane&15);
      const float lg = (ksum[ntl][r] - kcmp[ntl][r]) * INV_WS;
      lgout[(size_t)(tb+tok)*NE + eb + e] = lg;
    }
}

// Gating, 1 token per wave, grid T/4.
__global__ __launch_bounds__(256)
void gate(const float* __restrict__ lg, const float* __restrict__ bias,
          float* __restrict__ out, int T){
  const int tid = threadIdx.x, lane = tid & 63, wv = tid >> 6;
  const int t = blockIdx.x*4 + wv;
  const float4 bias4 = *(const float4*)(bias + 4*lane);
  const int g = lane >> 3;
  const float NEG_INF = -__builtin_inff();

  const float4 l4 = *(const float4*)(lg + (size_t)t*NE + 4*lane);
  float4 r4;   // uncorrected sigmoid scores
  r4.x = 1.f/(1.f + expf(-l4.x));
  r4.y = 1.f/(1.f + expf(-l4.y));
  r4.z = 1.f/(1.f + expf(-l4.z));
  r4.w = 1.f/(1.f + expf(-l4.w));
  float4 s4;   // corrected
  s4.x = r4.x + bias4.x; s4.y = r4.y + bias4.y;
  s4.z = r4.z + bias4.z; s4.w = r4.w + bias4.w;

  float m1 = s4.x, m2 = NEG_INF;
  if (s4.y > m1) { m2 = m1; m1 = s4.y; } else if (s4.y > m2) m2 = s4.y;
  if (s4.z > m1) { m2 = m1; m1 = s4.z; } else if (s4.z > m2) m2 = s4.z;
  if (s4.w > m1) { m2 = m1; m1 = s4.w; } else if (s4.w > m2) m2 = s4.w;
#pragma unroll
  for (int m = 1; m <= 4; m <<= 1) {
    const float o1 = __shfl_xor(m1, m);
    const float o2 = __shfl_xor(m2, m);
    const float nm1 = fmaxf(m1, o1);
    const float nm2 = fmaxf(fminf(m1, o1), fmaxf(m2, o2));
    m1 = nm1; m2 = nm2;
  }
  const float gs = m1 + m2;

  float gsv[8];
#pragma unroll
  for (int j = 0; j < 8; ++j) gsv[j] = __shfl(gs, j * 8);

  unsigned gm = 0;
#pragma unroll
  for (int r = 0; r < TOPKG; ++r) {
    float best = NEG_INF; int bj = 0;
#pragma unroll
    for (int j = 0; j < 8; ++j) {
      const bool avail = !((gm >> j) & 1u);
      if (avail && gsv[j] > best) { best = gsv[j]; bj = j; }
    }
    gm |= 1u << bj;
  }
  const bool allowed = (gm >> g) & 1u;

  float v0 = allowed ? s4.x : 0.f;
  float v1 = allowed ? s4.y : 0.f;
  float v2 = allowed ? s4.z : 0.f;
  float v3 = allowed ? s4.w : 0.f;

  float sumw = 0.f;
  int myidx = 0; float myraw = 0.f;
#pragma unroll
  for (int r = 0; r < TOPK; ++r) {
    float bv = v0; int bj = 0;
    if (v1 > bv) { bv = v1; bj = 1; }
    if (v2 > bv) { bv = v2; bj = 2; }
    if (v3 > bv) { bv = v3; bj = 3; }
    int bidx = 4 * lane + bj;
#pragma unroll
    for (int m = 1; m < 64; m <<= 1) {
      const float ov = __shfl_xor(bv, m);
      const int   oi = __shfl_xor(bidx, m);
      if (ov > bv || (ov == bv && oi < bidx)) { bv = ov; bidx = oi; }
    }
    const int oj = bidx & 3;
    const float cand = (oj == 0) ? r4.x
                     : (oj == 1) ? r4.y
                     : (oj == 2) ? r4.z
                     :             r4.w;
    const float raw = __shfl(cand, bidx >> 2);
    sumw += raw;
    if (lane == r) { myidx = bidx; myraw = raw; }
    if (lane == (bidx >> 2)) {
      if      (oj == 0) v0 = NEG_INF;
      else if (oj == 1) v1 = NEG_INF;
      else if (oj == 2) v2 = NEG_INF;
      else              v3 = NEG_INF;
    }
  }

  if (lane < TOPK) {
    out[(size_t)t * TOPK + lane] = (float)myidx;
    out[(size_t)T * TOPK + (size_t)t * TOPK + lane] = myraw / (sumw + 1e-20f) * 2.5f;
  }
}

extern "C" void kernel_launch(void* const* d_in, const int* in_sizes, int n_in,
                              void* d_out, int out_size, void* d_ws, size_t ws_size,
                              hipStream_t stream) {
  const float* hs   = (const float*)d_in[0];
  const float* wgt  = (const float*)d_in[1];
  const float* bias = (const float*)d_in[2];
  float* out = (float*)d_out;

  const int T = in_sizes[0] / HH;   // 8192

  unsigned short* bh = (unsigned short*)d_ws;
  unsigned short* bm = bh + (size_t)NE*HH;
  float* lgbuf = (float*)(bm + (size_t)NE*HH);   // 8.4 MB; total ws use 15.7 MB

  hipLaunchKernelGGL(prep_w, dim3(896), dim3(256), 0, stream, wgt, bh, bm);
  hipLaunchKernelGGL(gemm,   dim3(512), dim3(512), 0, stream, hs, bh, bm, lgbuf);
  hipLaunchKernelGGL(gate,   dim3(T/4), dim3(256), 0, stream, lgbuf, bias, out, T);
}

// Round 6
// 497.277 us; speedup vs baseline: 1.0963x; 1.0963x over previous
//
#include <hip/hip_runtime.h>
#include <cmath>

typedef __attribute__((ext_vector_type(8))) _Float16 half8;
typedef __attribute__((ext_vector_type(8))) unsigned short ushort8;
typedef __attribute__((ext_vector_type(4))) float f32x4;

#define HH 7168
#define NE 256
#define NQ 224        // K32 chunks
#define NITER 112     // 64-K iterations
#define TOPK 8
#define TOPKG 4
#define WSC 1024.f
#define INV_WS (1.f/1024.f)
#define C1 (1.f/2048.f)       // 2^-11
#define C2 (1.f/4194304.f)    // 2^-22

// 2-level f16 split: x = h + m*2^-11, residual ~2^-25|x|
__device__ __forceinline__ void split2(float x, unsigned short& h, unsigned short& m){
  const _Float16 hh = (_Float16)x;
  const float r = x - (float)hh;                 // exact
  const _Float16 mm = (_Float16)(r * 2048.f);
  h = __builtin_bit_cast(unsigned short, hh);
  m = __builtin_bit_cast(unsigned short, mm);
}

// W*1024 -> (h,m) f16 in MFMA B-fragment order, coalesced writes.
// slot(q,nt,L) holds B[k=32q+8(L>>4)+j][e=16nt+(L&15)], j=0..7.
__global__ __launch_bounds__(256) void prep_w(const float* __restrict__ wgt,
                                              unsigned short* __restrict__ bh,
                                              unsigned short* __restrict__ bm){
  const int b = blockIdx.x;                 // 896 = 16 nt * 56 q-groups
  const int nt = b & 15, qb = (b >> 4) * 4;
  const int w = threadIdx.x >> 6, L = threadIdx.x & 63;
  const int q = qb + w;
  const int e = nt*16 + (L & 15);
  const int k0 = 32*q + 8*(L >> 4);
  const float4 a0 = *(const float4*)(wgt + (size_t)e*HH + k0);
  const float4 a1 = *(const float4*)(wgt + (size_t)e*HH + k0 + 4);
  const float v[8] = {a0.x,a0.y,a0.z,a0.w,a1.x,a1.y,a1.z,a1.w};
  ushort8 h8, m8;
#pragma unroll
  for(int j=0;j<8;j++){ unsigned short hh,mm; split2(v[j]*WSC, hh, mm); h8[j]=hh; m8[j]=mm; }
  const size_t base = ((size_t)(q*16+nt)*64 + L)*8;
  *(ushort8*)(bh+base) = h8;
  *(ushort8*)(bm+base) = m8;
}

// ---------------- GEMM: 64tok x 128exp block, square 32x32 wave tiles ----------------
// 512 thr / 8 waves (2mtp x 4ntp), each wave owns 32tok x 32exp (2mt x 2ntl of 16x16).
// Read efficiency: 16 MFMA from 8 ds_read_b128 (full AxB fragment cross product),
// 1.5x fewer LDS reads per MAC than the 16x32 tile; B-DMA per CU halves (B shared
// by 64 tokens). Split2 staged exactly once per 64-K chunk (no R2 redundancy).
// Grid 256 -> 1 block/CU (96 KB LDS), 2 waves/SIMD; simple R2 schedule:
// issue DMA+ga at top, compute, stage, __syncthreads (full drain = depth-1 B).
// Per-element MFMA order and Kahan flush points identical to R2 -> bit-identical.
#define AB(aw,lvl,mt,q,row) ((((((aw)*2+(lvl))*4+(mt))*2+(q))*64+(row))*16)
#define BB(lvl,q,nt) ((((lvl)*2+(q))*8+(nt))<<10)
__device__ __forceinline__ int swz(int bo){ return bo ^ (((bo >> 8) & 7) << 4); }

__device__ __forceinline__ void glds16(const void* g, void* l){
  __builtin_amdgcn_global_load_lds(
      (const __attribute__((address_space(1))) unsigned int*)g,
      (__attribute__((address_space(3))) unsigned int*)l, 16, 0, 0);
}

__global__ __launch_bounds__(512,2)
void gemm(const float* __restrict__ hs,
          const unsigned short* __restrict__ bhp,
          const unsigned short* __restrict__ bmp,
          float* __restrict__ lgout){
  __shared__ __align__(16) unsigned char blds[65536];  // 2buf x (2lvl x 2q x 8nt) x 1KB
  __shared__ __align__(16) unsigned char alds[32768];  // 2buf x 2lvl x 4mt x 2q x 64row x 16B

  const int tid = threadIdx.x, lane = tid & 63, w = tid >> 6;
  const int b = blockIdx.x;                // 256 blocks
  const int slice = (b >> 2) & 1;          // XCD 0-3 -> slice0, 4-7 -> slice1 (L2-resident)
  const int tg = (b >> 3)*4 + (b & 3);     // 0..127
  const int tb = tg*64, eb = slice*128;
  const int mtp = w >> 2, ntp = w & 3;     // wave tile: mt {2mtp,2mtp+1} x ntl {2ntp,2ntp+1}

  f32x4 ksum[2][2], kcmp[2][2], c0[2][2], c1[2][2], c2[2][2];
#pragma unroll
  for(int a=0;a<2;a++)
#pragma unroll
    for(int c=0;c<2;c++){ ksum[a][c]=f32x4{0,0,0,0}; kcmp[a][c]=f32x4{0,0,0,0}; }

  // A staging: thread -> token tid>>3 (64 tok), 8 consecutive k at (tid&7)*8
  const int tokS = tid >> 3, kidx = tid & 7;
  const int mtS = tokS >> 4, m16S = tokS & 15;
  const int qS = kidx >> 2, kgS = kidx & 3;
  const int rowS = kgS*16 + m16S;
  const float* agp = hs + (size_t)(tb + tokS)*HH + kidx*8;
  float4 ga[2];

  auto stage = [&](int aw){
    unsigned short h[8], m[8];
    const float* gv = (const float*)ga;
#pragma unroll
    for(int p=0;p<8;p++) split2(gv[p], h[p], m[p]);
    ushort8 h8, m8;
#pragma unroll
    for(int j=0;j<8;j++){ h8[j]=h[j]; m8[j]=m[j]; }
    *(ushort8*)&alds[swz(AB(aw,0,mtS,qS,rowS))] = h8;
    *(ushort8*)&alds[swz(AB(aw,1,mtS,qS,rowS))] = m8;
  };

  // B staging: 32 slots (2lvl x 2q x 8nt) of 1KB per buf, 4 glds16 per wave
  auto bstage = [&](int bufoff, int inext){
#pragma unroll
    for(int j=0;j<4;j++){
      const int sid = w*4 + j;
      const int lvl = sid >> 4, q = (sid >> 3) & 1, nt = sid & 7;
      const int q32 = 2*inext + q;
      const unsigned short* src = (lvl ? bmp : bhp)
          + ((size_t)((q32*16 + slice*8 + nt)*64 + lane))*8;
      glds16(src, &blds[bufoff + BB(lvl,q,nt)]);
    }
  };

  auto compute = [&](int aw, int s, int bbuf){
    half8 ah[2], am[2];
#pragma unroll
    for(int mtl=0;mtl<2;mtl++){
      const int mt = mtp*2 + mtl;
      ah[mtl] = *(const half8*)&alds[swz(AB(aw,0,mt,s,lane))];
      am[mtl] = *(const half8*)&alds[swz(AB(aw,1,mt,s,lane))];
    }
    half8 Bh[2], Bm[2];
#pragma unroll
    for(int ntl=0;ntl<2;ntl++){
      Bh[ntl] = *(const half8*)&blds[bbuf + BB(0,s,ntp*2+ntl) + lane*16];
      Bm[ntl] = *(const half8*)&blds[bbuf + BB(1,s,ntp*2+ntl) + lane*16];
    }
    __builtin_amdgcn_s_setprio(1);
#pragma unroll
    for(int mtl=0;mtl<2;mtl++)
#pragma unroll
      for(int ntl=0;ntl<2;ntl++){
        c0[mtl][ntl] = __builtin_amdgcn_mfma_f32_16x16x32_f16(ah[mtl], Bh[ntl], c0[mtl][ntl], 0,0,0);
        c1[mtl][ntl] = __builtin_amdgcn_mfma_f32_16x16x32_f16(ah[mtl], Bm[ntl], c1[mtl][ntl], 0,0,0);
        c1[mtl][ntl] = __builtin_amdgcn_mfma_f32_16x16x32_f16(am[mtl], Bh[ntl], c1[mtl][ntl], 0,0,0);
        c2[mtl][ntl] = __builtin_amdgcn_mfma_f32_16x16x32_f16(am[mtl], Bm[ntl], c2[mtl][ntl], 0,0,0);
      }
    __builtin_amdgcn_s_setprio(0);
  };

  // ---- prologue: A chunk 0 + B q-pair 0 into buf 0
  ga[0] = *(const float4*)agp;
  ga[1] = *(const float4*)(agp + 4);
  bstage(0, 0);
  stage(0);
  __syncthreads();

#pragma unroll 1
  for(int i=0;i<NITER;i++){
    const int cur = i & 1, nb = cur ^ 1;
    const bool more = (i+1 < NITER);
    if(more){
      const float* ap = agp + (size_t)(i+1)*64;
      ga[0] = *(const float4*)ap;
      ga[1] = *(const float4*)(ap + 4);
      bstage(nb*32768, i+1);
    }
    if((i & 1) == 0){
#pragma unroll
      for(int a=0;a<2;a++)
#pragma unroll
        for(int c=0;c<2;c++){ c0[a][c]=f32x4{0,0,0,0}; c1[a][c]=f32x4{0,0,0,0}; c2[a][c]=f32x4{0,0,0,0}; }
    }
    compute(cur, 0, cur*32768);
    compute(cur, 1, cur*32768);
    if(more) stage(nb);
    if(i & 1){
      // Kahan flush of the completed 128-K window (same order as R2 -> bit-identical)
#pragma unroll
      for(int a=0;a<2;a++)
#pragma unroll
        for(int c=0;c<2;c++)
#pragma unroll
          for(int r=0;r<4;r++){
            const float v = c0[a][c][r] + c1[a][c][r]*C1 + c2[a][c][r]*C2;
            const float y = v - kcmp[a][c][r];
            const float t = ksum[a][c][r] + y;
            kcmp[a][c][r] = (t - ksum[a][c][r]) - y;
            ksum[a][c][r] = t;
          }
    }
    __syncthreads();
  }

  // epilogue: C layout col=lane&15 (expert), row=(lane>>4)*4+r (token); undo W scale
#pragma unroll
  for(int mtl=0;mtl<2;mtl++)
#pragma unroll
    for(int ntl=0;ntl<2;ntl++)
#pragma unroll
      for(int r=0;r<4;r++){
        const int tok = (mtp*2+mtl)*16 + (lane>>4)*4 + r;
        const int e = (ntp*2+ntl)*16 + (lane&15);
        const float lg = (ksum[mtl][ntl][r] - kcmp[mtl][ntl][r]) * INV_WS;
        lgout[(size_t)(tb+tok)*NE + eb + e] = lg;
      }
}

// Gating, 1 token per wave, grid T/4.
__global__ __launch_bounds__(256)
void gate(const float* __restrict__ lg, const float* __restrict__ bias,
          float* __restrict__ out, int T){
  const int tid = threadIdx.x, lane = tid & 63, wv = tid >> 6;
  const int t = blockIdx.x*4 + wv;
  const float4 bias4 = *(const float4*)(bias + 4*lane);
  const int g = lane >> 3;
  const float NEG_INF = -__builtin_inff();

  const float4 l4 = *(const float4*)(lg + (size_t)t*NE + 4*lane);
  float4 r4;   // uncorrected sigmoid scores
  r4.x = 1.f/(1.f + expf(-l4.x));
  r4.y = 1.f/(1.f + expf(-l4.y));
  r4.z = 1.f/(1.f + expf(-l4.z));
  r4.w = 1.f/(1.f + expf(-l4.w));
  float4 s4;   // corrected
  s4.x = r4.x + bias4.x; s4.y = r4.y + bias4.y;
  s4.z = r4.z + bias4.z; s4.w = r4.w + bias4.w;

  float m1 = s4.x, m2 = NEG_INF;
  if (s4.y > m1) { m2 = m1; m1 = s4.y; } else if (s4.y > m2) m2 = s4.y;
  if (s4.z > m1) { m2 = m1; m1 = s4.z; } else if (s4.z > m2) m2 = s4.z;
  if (s4.w > m1) { m2 = m1; m1 = s4.w; } else if (s4.w > m2) m2 = s4.w;
#pragma unroll
  for (int m = 1; m <= 4; m <<= 1) {
    const float o1 = __shfl_xor(m1, m);
    const float o2 = __shfl_xor(m2, m);
    const float nm1 = fmaxf(m1, o1);
    const float nm2 = fmaxf(fminf(m1, o1), fmaxf(m2, o2));
    m1 = nm1; m2 = nm2;
  }
  const float gs = m1 + m2;

  float gsv[8];
#pragma unroll
  for (int j = 0; j < 8; ++j) gsv[j] = __shfl(gs, j * 8);

  unsigned gm = 0;
#pragma unroll
  for (int r = 0; r < TOPKG; ++r) {
    float best = NEG_INF; int bj = 0;
#pragma unroll
    for (int j = 0; j < 8; ++j) {
      const bool avail = !((gm >> j) & 1u);
      if (avail && gsv[j] > best) { best = gsv[j]; bj = j; }
    }
    gm |= 1u << bj;
  }
  const bool allowed = (gm >> g) & 1u;

  float v0 = allowed ? s4.x : 0.f;
  float v1 = allowed ? s4.y : 0.f;
  float v2 = allowed ? s4.z : 0.f;
  float v3 = allowed ? s4.w : 0.f;

  float sumw = 0.f;
  int myidx = 0; float myraw = 0.f;
#pragma unroll
  for (int r = 0; r < TOPK; ++r) {
    float bv = v0; int bj = 0;
    if (v1 > bv) { bv = v1; bj = 1; }
    if (v2 > bv) { bv = v2; bj = 2; }
    if (v3 > bv) { bv = v3; bj = 3; }
    int bidx = 4 * lane + bj;
#pragma unroll
    for (int m = 1; m < 64; m <<= 1) {
      const float ov = __shfl_xor(bv, m);
      const int   oi = __shfl_xor(bidx, m);
      if (ov > bv || (ov == bv && oi < bidx)) { bv = ov; bidx = oi; }
    }
    const int oj = bidx & 3;
    const float cand = (oj == 0) ? r4.x
                     : (oj == 1) ? r4.y
                     : (oj == 2) ? r4.z
                     :             r4.w;
    const float raw = __shfl(cand, bidx >> 2);
    sumw += raw;
    if (lane == r) { myidx = bidx; myraw = raw; }
    if (lane == (bidx >> 2)) {
      if      (oj == 0) v0 = NEG_INF;
      else if (oj == 1) v1 = NEG_INF;
      else if (oj == 2) v2 = NEG_INF;
      else              v3 = NEG_INF;
    }
  }

  if (lane < TOPK) {
    out[(size_t)t * TOPK + lane] = (float)myidx;
    out[(size_t)T * TOPK + (size_t)t * TOPK + lane] = myraw / (sumw + 1e-20f) * 2.5f;
  }
}

extern "C" void kernel_launch(void* const* d_in, const int* in_sizes, int n_in,
                              void* d_out, int out_size, void* d_ws, size_t ws_size,
                              hipStream_t stream) {
  const float* hs   = (const float*)d_in[0];
  const float* wgt  = (const float*)d_in[1];
  const float* bias = (const float*)d_in[2];
  float* out = (float*)d_out;

  const int T = in_sizes[0] / HH;   // 8192

  unsigned short* bh = (unsigned short*)d_ws;
  unsigned short* bm = bh + (size_t)NE*HH;
  float* lgbuf = (float*)(bm + (size_t)NE*HH);   // 8.4 MB; total ws use 15.7 MB

  hipLaunchKernelGGL(prep_w, dim3(896), dim3(256), 0, stream, wgt, bh, bm);
  hipLaunchKernelGGL(gemm,   dim3(256), dim3(512), 0, stream, hs, bh, bm, lgbuf);
  hipLaunchKernelGGL(gate,   dim3(T/4), dim3(256), 0, stream, lgbuf, bias, out, T);
}